// Round 3
// baseline (271.983 us; speedup 1.0000x reference)
//
#include <hip/hip_runtime.h>
#include <hip/hip_bf16.h>

// Embedding gather: out[b,s,:] = W[x[b,s],:]
//   x: (4, 4096) int32      -> 16384 rows
//   W: (50257, 1024) float32
//   out: (4, 4096, 1024) float32
//
// Round 2 -> 3 change: one block per 8 rows (was 1 row). Each thread issues
// 8 independent float4 loads (one per row) before storing — deep MLP instead
// of a single dependent load chain per block; 2048 workgroups instead of 16384.

static constexpr int D_VEC4 = 256;        // 1024 floats / 4 per row
static constexpr int ROWS_PER_BLOCK = 8;  // 32 KiB contiguous output per block

__global__ __launch_bounds__(256) void embed_gather_kernel(
    const int* __restrict__ x,
    const float4* __restrict__ W,
    float4* __restrict__ out,
    int n_rows) {
    const int tid = threadIdx.x;
    for (int row0 = blockIdx.x * ROWS_PER_BLOCK; row0 < n_rows;
         row0 += gridDim.x * ROWS_PER_BLOCK) {
        // Block-uniform index loads (compiler scalarizes to s_load).
        int idx[ROWS_PER_BLOCK];
#pragma unroll
        for (int r = 0; r < ROWS_PER_BLOCK; ++r) {
            int row = row0 + r;
            idx[r] = (row < n_rows) ? x[row] : 0;
        }
        // 8 independent gathered loads in flight per thread.
        float4 v[ROWS_PER_BLOCK];
#pragma unroll
        for (int r = 0; r < ROWS_PER_BLOCK; ++r) {
            v[r] = W[(size_t)idx[r] * D_VEC4 + tid];
        }
        // 8 coalesced stores; block's output region is 32 KiB contiguous.
#pragma unroll
        for (int r = 0; r < ROWS_PER_BLOCK; ++r) {
            int row = row0 + r;
            if (row < n_rows) out[(size_t)row * D_VEC4 + tid] = v[r];
        }
    }
}

extern "C" void kernel_launch(void* const* d_in, const int* in_sizes, int n_in,
                              void* d_out, int out_size, void* d_ws, size_t ws_size,
                              hipStream_t stream) {
    const int* x = (const int*)d_in[0];        // (B*S,) int32 indices
    const float4* W = (const float4*)d_in[1];  // (VOCAB, 1024) f32 as float4
    float4* out = (float4*)d_out;              // (B*S, 1024) f32 as float4

    const int n_rows = in_sizes[0];            // B*S = 16384

    const int block = 256;
    int grid = (n_rows + ROWS_PER_BLOCK - 1) / ROWS_PER_BLOCK;  // 2048
    embed_gather_kernel<<<grid, block, 0, stream>>>(x, W, out, n_rows);
}